// Round 1
// baseline (401.170 us; speedup 1.0000x reference)
//
#include <hip/hip_runtime.h>
#include <stdint.h>

typedef float f32x4 __attribute__((ext_vector_type(4)));
typedef short bf16x8 __attribute__((ext_vector_type(8)));

#define N_L 4096
#define N_C 512
#define N_B 8
#define N_ROWS 32768   // B*L

__device__ __forceinline__ float bf2f(unsigned short h){
  union { unsigned int u; float f; } v; v.u = ((unsigned int)h) << 16; return v.f;
}
__device__ __forceinline__ unsigned short f2bf(float f){
  union { float f; unsigned int u; } v; v.f = f;
  return (unsigned short)((v.u + 0x7fffu + ((v.u >> 16) & 1u)) >> 16);
}

typedef __attribute__((address_space(1))) const unsigned int ga_u32;
typedef __attribute__((address_space(3))) unsigned int ls_u32;
__device__ __forceinline__ void async_load16(const void* g, void* l){
  __builtin_amdgcn_global_load_lds((ga_u32*)g, (ls_u32*)l, 16, 0, 0);
}

// ---------------------------------------------------------------------------
// prep: fp32 weights -> bf16, 5 matrices of 512x512
__global__ __launch_bounds__(256) void k_prep_w(
    const float* __restrict__ w0, const float* __restrict__ w1,
    const float* __restrict__ w2, const float* __restrict__ w3,
    const float* __restrict__ w4, unsigned short* __restrict__ out)
{
  int i = blockIdx.x * 256 + threadIdx.x;      // 0..262143
  const float* w = (blockIdx.y == 0) ? w0 : (blockIdx.y == 1) ? w1 :
                   (blockIdx.y == 2) ? w2 : (blockIdx.y == 3) ? w3 : w4;
  out[(size_t)blockIdx.y * 262144 + i] = f2bf(w[i]);
}

// ---------------------------------------------------------------------------
// build xs_bf[b][l][c] = bf16( x[b][c][l] + pos[l][c] )   (64x64 LDS transpose)
__global__ __launch_bounds__(256) void k_build_xs(
    const float* __restrict__ x, const float* __restrict__ pos,
    unsigned short* __restrict__ xsb)
{
  __shared__ float tile[64][65];
  const int lt = blockIdx.x, ct = blockIdx.y, b = blockIdx.z;
  const int t = threadIdx.x;
  const int rr = t >> 3, c8 = (t & 7) * 8;
  #pragma unroll
  for (int pass = 0; pass < 2; pass++){
    int r = rr + pass * 32;                                   // channel-local
    const float* src = x + ((size_t)b * 512 + ct*64 + r) * 4096 + lt*64 + c8;
    f32x4 v0 = *(const f32x4*)src;
    f32x4 v1 = *(const f32x4*)(src + 4);
    #pragma unroll
    for (int s = 0; s < 4; s++){ tile[r][c8+s] = v0[s]; tile[r][c8+4+s] = v1[s]; }
  }
  __syncthreads();
  #pragma unroll
  for (int pass = 0; pass < 2; pass++){
    int ll = rr + pass * 32;                                  // l-local
    int gl = lt*64 + ll;
    const float* pp = pos + (size_t)gl * 512 + ct*64 + c8;
    bf16x8 hv;
    #pragma unroll
    for (int s = 0; s < 8; s++)
      hv[s] = (short)f2bf(tile[c8+s][ll] + pp[s]);
    *(bf16x8*)(xsb + ((size_t)b * 4096 + gl) * 512 + ct*64 + c8) = hv;
  }
}

// ---------------------------------------------------------------------------
// generic bf16 transpose: in[z][R][C] -> out[z][C][R]
__global__ __launch_bounds__(256) void k_transpose_bf(
    const unsigned short* __restrict__ in, unsigned short* __restrict__ out,
    int R, int C)
{
  __shared__ float tile[64][65];
  const int rt = blockIdx.x, ct = blockIdx.y, z = blockIdx.z;
  const unsigned short* src = in  + (size_t)z * R * C;
  unsigned short*       dst = out + (size_t)z * R * C;
  const int t = threadIdx.x;
  const int rr = t >> 3, c8 = (t & 7) * 8;
  #pragma unroll
  for (int pass = 0; pass < 2; pass++){
    int r = rr + pass * 32;
    bf16x8 v = *(const bf16x8*)(src + (size_t)(rt*64 + r) * C + ct*64 + c8);
    #pragma unroll
    for (int s = 0; s < 8; s++) tile[r][c8+s] = bf2f((unsigned short)v[s]);
  }
  __syncthreads();
  #pragma unroll
  for (int pass = 0; pass < 2; pass++){
    int c = rr + pass * 32;
    bf16x8 hv;
    #pragma unroll
    for (int s = 0; s < 8; s++) hv[s] = (short)f2bf(tile[c8+s][c]);
    *(bf16x8*)(dst + (size_t)(ct*64 + c) * R + rt*64 + c8) = hv;
  }
}

// ---------------------------------------------------------------------------
// diagKV[b][c] = sum_l K*V ; Ksum[b][c] = sum_l K     (K,V bf16 [B*L][C])
__global__ __launch_bounds__(256) void k_reduce_kv(
    const unsigned short* __restrict__ Kb, const unsigned short* __restrict__ Vb,
    float* __restrict__ diag, float* __restrict__ ksum)
{
  const int c0 = blockIdx.x * 64, b = blockIdx.y, lz = blockIdx.z * 512;
  const int t = threadIdx.x;
  const int c = c0 + (t & 63), lo = t >> 6;
  float d = 0.f, s = 0.f;
  for (int l = lo; l < 512; l += 4){
    size_t idx = ((size_t)b * 4096 + lz + l) * 512 + c;
    float kk = bf2f(Kb[idx]);
    float vv = bf2f(Vb[idx]);
    d += kk * vv; s += kk;
  }
  __shared__ float sd[256], sk[256];
  sd[t] = d; sk[t] = s;
  __syncthreads();
  if (t < 64){
    d = sd[t] + sd[t+64] + sd[t+128] + sd[t+192];
    s = sk[t] + sk[t+64] + sk[t+128] + sk[t+192];
    atomicAdd(&diag[b*512 + c0 + t], d);
    atomicAdd(&ksum[b*512 + c0 + t], s);
  }
}

// ---------------------------------------------------------------------------
// per row: Z = 1/sum_c Q*(Ksum+eps); r0 = Q*diagKV*Z  (bf16 out)
__global__ __launch_bounds__(256) void k_z_r0(
    const unsigned short* __restrict__ Qb, const float* __restrict__ ksum,
    const float* __restrict__ diag, unsigned short* __restrict__ r0)
{
  const int row = blockIdx.x * 4 + (threadIdx.x >> 6);
  const int lane = threadIdx.x & 63;
  const int b = row >> 12;
  bf16x8 q = *(const bf16x8*)(Qb + (size_t)row * 512 + lane * 8);
  float qf[8];
  #pragma unroll
  for (int s = 0; s < 8; s++) qf[s] = bf2f((unsigned short)q[s]);
  f32x4 k0 = *(const f32x4*)(ksum + b*512 + lane*8);
  f32x4 k1 = *(const f32x4*)(ksum + b*512 + lane*8 + 4);
  f32x4 d0 = *(const f32x4*)(diag + b*512 + lane*8);
  f32x4 d1 = *(const f32x4*)(diag + b*512 + lane*8 + 4);
  float den = 0.f;
  #pragma unroll
  for (int s = 0; s < 4; s++) den += qf[s]   * (k0[s] + 1e-6f);
  #pragma unroll
  for (int s = 0; s < 4; s++) den += qf[4+s] * (k1[s] + 1e-6f);
  #pragma unroll
  for (int m = 1; m < 64; m <<= 1) den += __shfl_xor(den, m);
  float Z = 1.0f / den;
  bf16x8 hv;
  #pragma unroll
  for (int s = 0; s < 4; s++) hv[s]   = (short)f2bf(qf[s]   * d0[s] * Z);
  #pragma unroll
  for (int s = 0; s < 4; s++) hv[4+s] = (short)f2bf(qf[4+s] * d1[s] * Z);
  *(bf16x8*)(r0 + (size_t)row * 512 + lane * 8) = hv;
}

// ---------------------------------------------------------------------------
// row softmax: S[row][0..511] fp32 -> mid bf16
__global__ __launch_bounds__(64) void k_softmax(
    const float* __restrict__ S, unsigned short* __restrict__ mid)
{
  const size_t row = blockIdx.x;
  const int lane = threadIdx.x;
  const float* p = S + row * 512 + lane * 8;
  f32x4 v0 = *(const f32x4*)p, v1 = *(const f32x4*)(p + 4);
  float mx = v0[0];
  #pragma unroll
  for (int s = 1; s < 4; s++) mx = fmaxf(mx, v0[s]);
  #pragma unroll
  for (int s = 0; s < 4; s++) mx = fmaxf(mx, v1[s]);
  #pragma unroll
  for (int m = 1; m < 64; m <<= 1) mx = fmaxf(mx, __shfl_xor(mx, m));
  float e[8]; float sum = 0.f;
  #pragma unroll
  for (int s = 0; s < 4; s++){ e[s]   = __expf(v0[s] - mx); sum += e[s]; }
  #pragma unroll
  for (int s = 0; s < 4; s++){ e[4+s] = __expf(v1[s] - mx); sum += e[4+s]; }
  #pragma unroll
  for (int m = 1; m < 64; m <<= 1) sum += __shfl_xor(sum, m);
  float inv = 1.0f / sum;
  bf16x8 hv;
  #pragma unroll
  for (int s = 0; s < 8; s++) hv[s] = (short)f2bf(e[s] * inv);
  *(bf16x8*)(mid + row * 512 + lane * 8) = hv;
}

// ---------------------------------------------------------------------------
// bt-GEMM core: C[128x128] = A[M,K] @ Bt[N,K]^T, bf16 in fp32 acc.
// EPI 0: out bf16 = acc+bias       (proj, no relu)
// EPI 1: out bf16 = relu(acc+bias) (proj, relu)
// EPI 2: out fp32 S (per-batch z)  (mid logits)
// EPI 3: y = xs + gamma*acc in-place bf16 + BN sum/sumsq atomics
template<int EPI>
__global__ __launch_bounds__(256) void gemm_bt(
    const unsigned short* __restrict__ A,
    const unsigned short* __restrict__ Bt,
    float* __restrict__ outf,
    unsigned short* __restrict__ outh,
    const float* __restrict__ bias,
    int K,
    const float* __restrict__ gamma_p,
    float* __restrict__ bnS,
    float* __restrict__ bnQ)
{
  __shared__ unsigned short Alds[128*64];
  __shared__ unsigned short Blds[128*64];
  const int tid = threadIdx.x;
  const int lane = tid & 63;
  const int wave = tid >> 6;
  const int wm = wave >> 1, wn = wave & 1;
  const int mtile = blockIdx.x, ntile = blockIdx.y;
  const int m0 = mtile * 128, n0 = ntile * 128;

  const unsigned short* Ae = A;
  const unsigned short* Be = Bt;
  int z = 0;
  if (EPI == 2){ z = blockIdx.z; Ae += (size_t)z * 512 * (size_t)K; Be += (size_t)z * 512 * (size_t)K; }
  if (EPI == 3){ z = mtile >> 5; Be += (size_t)z * 512 * (size_t)K; }

  // staging decomposition: 1024 16B-chunks per matrix, 4 per thread.
  // LDS is linear; global source is XOR-swizzled so swizzled reads see
  // conflict-free banks (rule #21: linear dest + inv-swz source + swz read).
  size_t aoff[4], boff[4];
  int ldsq[4];
  #pragma unroll
  for (int i = 0; i < 4; i++){
    int q  = i*4 + wave;
    int ch = q*64 + lane;
    int m  = ch >> 3, p = ch & 7;
    int lc = p ^ (m & 7);
    aoff[i] = (size_t)(m0 + m) * K + lc*8;
    boff[i] = (size_t)(n0 + m) * K + lc*8;
    ldsq[i] = q * 1024;
  }

  f32x4 acc[4][4];
  const f32x4 vzero = {0.f, 0.f, 0.f, 0.f};
  #pragma unroll
  for (int i = 0; i < 4; i++)
    #pragma unroll
    for (int j = 0; j < 4; j++) acc[i][j] = vzero;

  int arow[4], brow[4];
  #pragma unroll
  for (int f = 0; f < 4; f++){
    arow[f] = (wm*64 + f*16 + (lane & 15)) * 64;
    brow[f] = (wn*64 + f*16 + (lane & 15)) * 64;
  }
  const int kg = lane >> 4;
  const int l7 = lane & 7;

  const int nkt = K >> 6;
  for (int kt = 0; kt < nkt; kt++){
    #pragma unroll
    for (int i = 0; i < 4; i++){
      async_load16(Ae + aoff[i] + kt*64, (char*)Alds + ldsq[i]);
      async_load16(Be + boff[i] + kt*64, (char*)Blds + ldsq[i]);
    }
    __syncthreads();
    #pragma unroll
    for (int ks = 0; ks < 2; ks++){
      bf16x8 a[4], b[4];
      const int pa = (ks*4 + kg) ^ l7;
      #pragma unroll
      for (int f = 0; f < 4; f++){
        a[f] = *(const bf16x8*)&Alds[arow[f] + pa*8];
        b[f] = *(const bf16x8*)&Blds[brow[f] + pa*8];
      }
      #pragma unroll
      for (int i = 0; i < 4; i++)
        #pragma unroll
        for (int j = 0; j < 4; j++)
          acc[i][j] = __builtin_amdgcn_mfma_f32_16x16x32_bf16(a[i], b[j], acc[i][j], 0, 0, 0);
    }
    __syncthreads();
  }

  const int lr = lane >> 4;      // C/D: col = lane&15, row = lr*4 + q  (m89)
  const int lc16 = lane & 15;

  if constexpr (EPI == 0 || EPI == 1){
    #pragma unroll
    for (int j = 0; j < 4; j++){
      int cidx = n0 + wn*64 + j*16 + lc16;
      float bb = bias[cidx];
      #pragma unroll
      for (int i = 0; i < 4; i++){
        int r = m0 + wm*64 + i*16 + lr*4;
        #pragma unroll
        for (int q = 0; q < 4; q++){
          float v = acc[i][j][q] + bb;
          if (EPI == 1) v = v > 0.f ? v : 0.f;
          outh[(size_t)(r + q) * 512 + cidx] = f2bf(v);
        }
      }
    }
  } else if constexpr (EPI == 2){
    #pragma unroll
    for (int j = 0; j < 4; j++){
      int cidx = n0 + wn*64 + j*16 + lc16;
      #pragma unroll
      for (int i = 0; i < 4; i++){
        int r = m0 + wm*64 + i*16 + lr*4;
        #pragma unroll
        for (int q = 0; q < 4; q++)
          outf[(size_t)z * 262144 + (size_t)(r + q) * 512 + cidx] = acc[i][j][q];
      }
    }
  } else {
    float g = gamma_p[0];
    float sc[4] = {0.f,0.f,0.f,0.f}, sq[4] = {0.f,0.f,0.f,0.f};
    #pragma unroll
    for (int j = 0; j < 4; j++){
      int cidx = n0 + wn*64 + j*16 + lc16;
      #pragma unroll
      for (int i = 0; i < 4; i++){
        int r = m0 + wm*64 + i*16 + lr*4;
        #pragma unroll
        for (int q = 0; q < 4; q++){
          size_t idx = (size_t)(r + q) * 512 + cidx;
          float y = bf2f(outh[idx]) + g * acc[i][j][q];
          outh[idx] = f2bf(y);
          sc[j] += y; sq[j] += y * y;
        }
      }
    }
    #pragma unroll
    for (int j = 0; j < 4; j++){
      #pragma unroll
      for (int m = 16; m < 64; m <<= 1){
        sc[j] += __shfl_xor(sc[j], m);
        sq[j] += __shfl_xor(sq[j], m);
      }
    }
    __syncthreads();
    float* sS = (float*)(void*)Alds;   // 128 floats
    float* sQ = (float*)(void*)Blds;
    if (tid < 128){ sS[tid] = 0.f; sQ[tid] = 0.f; }
    __syncthreads();
    if (lr == 0){
      #pragma unroll
      for (int j = 0; j < 4; j++){
        atomicAdd(&sS[wn*64 + j*16 + lc16], sc[j]);
        atomicAdd(&sQ[wn*64 + j*16 + lc16], sq[j]);
      }
    }
    __syncthreads();
    if (tid < 128){
      atomicAdd(&bnS[n0 + tid], sS[tid]);
      atomicAdd(&bnQ[n0 + tid], sQ[tid]);
    }
  }
}

// ---------------------------------------------------------------------------
// finalize: y[b][l][c] bf16 -> out[b][c][l] fp32, BN affine + relu
__global__ __launch_bounds__(256) void k_bn_finalize(
    const unsigned short* __restrict__ y, const float* __restrict__ bnS,
    const float* __restrict__ bnQ, const float* __restrict__ bnw,
    const float* __restrict__ bnb, float* __restrict__ out)
{
  __shared__ float tile[64][65];
  __shared__ float scale_s[64], shift_s[64];
  const int lt = blockIdx.x, ct = blockIdx.y, b = blockIdx.z;
  const int t = threadIdx.x;
  if (t < 64){
    int c = ct*64 + t;
    float s = bnS[c], q = bnQ[c];
    float mean = s * (1.0f / 32768.0f);
    float var  = q * (1.0f / 32768.0f) - mean * mean;
    float inv  = rsqrtf(var + 1e-5f);
    float scv  = bnw[c] * inv;
    scale_s[t] = scv;
    shift_s[t] = bnb[c] - mean * scv;
  }
  const int rr = t >> 3, c8 = (t & 7) * 8;
  #pragma unroll
  for (int pass = 0; pass < 2; pass++){
    int l = rr + pass * 32;
    bf16x8 v = *(const bf16x8*)(y + ((size_t)b * 4096 + lt*64 + l) * 512 + ct*64 + c8);
    #pragma unroll
    for (int s = 0; s < 8; s++) tile[l][c8+s] = bf2f((unsigned short)v[s]);
  }
  __syncthreads();
  #pragma unroll
  for (int pass = 0; pass < 2; pass++){
    int c = rr + pass * 32;
    float scv = scale_s[c], sh = shift_s[c];
    f32x4 o0, o1;
    #pragma unroll
    for (int s = 0; s < 4; s++){
      float v = tile[c8+s][c] * scv + sh;     o0[s] = v > 0.f ? v : 0.f;
      float w = tile[c8+4+s][c] * scv + sh;   o1[s] = w > 0.f ? w : 0.f;
    }
    float* dp = out + ((size_t)b * 512 + ct*64 + c) * 4096 + lt*64 + c8;
    *(f32x4*)dp = o0;
    *(f32x4*)(dp + 4) = o1;
  }
}

// ---------------------------------------------------------------------------
extern "C" void kernel_launch(void* const* d_in, const int* in_sizes, int n_in,
                              void* d_out, int out_size, void* d_ws, size_t ws_size,
                              hipStream_t stream)
{
  const float* x    = (const float*)d_in[0];
  const float* pos  = (const float*)d_in[1];
  const float* Wq   = (const float*)d_in[2];
  const float* bq   = (const float*)d_in[3];
  const float* Wk   = (const float*)d_in[4];
  const float* bk   = (const float*)d_in[5];
  const float* Wv   = (const float*)d_in[6];
  const float* bv   = (const float*)d_in[7];
  const float* Wq1  = (const float*)d_in[8];
  const float* bq1  = (const float*)d_in[9];
  const float* Wk1  = (const float*)d_in[10];
  const float* bk1  = (const float*)d_in[11];
  const float* gam  = (const float*)d_in[12];
  const float* bnw  = (const float*)d_in[13];
  const float* bnb  = (const float*)d_in[14];
  float* out = (float*)d_out;
  char* ws = (char*)d_ws;

  const size_t MB = 1ull << 20;
  const size_t OFF_XSB  = 0;                 // 32MB  xs_bf, later y (in-place)
  const size_t OFF_QB   = 32*MB;             // 32MB  Q bf16
  const size_t OFF_Q1   = 64*MB;             // 32MB  Q1 bf16, later r0
  const size_t OFF_K1   = 96*MB;             // 32MB  K1 bf16, later S/mid/midT
  const size_t OFF_Q1T  = 128*MB;            // 32MB
  const size_t OFF_K1T  = 160*MB;            // 32MB
  const size_t OFF_WBF  = 192*MB;            // 2.5MB
  const size_t OFF_DIAG = 195*MB;            // 16KB
  const size_t OFF_KSUM = OFF_DIAG + 16384;  // 16KB
  const size_t OFF_BNS  = OFF_KSUM + 16384;  // 2KB
  const size_t OFF_BNQ  = OFF_BNS + 2048;    // 2KB
  const size_t WS_NEED  = OFF_BNQ + 2048;
  if (ws_size < WS_NEED) return;

  unsigned short* xsb  = (unsigned short*)(ws + OFF_XSB);
  unsigned short* Qb   = (unsigned short*)(ws + OFF_QB);
  unsigned short* Q1   = (unsigned short*)(ws + OFF_Q1);
  unsigned short* r0   = Q1;                              // alias after Q1T
  unsigned short* K1   = (unsigned short*)(ws + OFF_K1);
  float*          Sf   = (float*)(ws + OFF_K1);           // alias after K1T (8MB)
  unsigned short* midb = (unsigned short*)(ws + OFF_K1 + 8*MB);   // 4MB
  unsigned short* midT = (unsigned short*)(ws + OFF_K1 + 12*MB);  // 4MB
  unsigned short* Q1T  = (unsigned short*)(ws + OFF_Q1T);
  unsigned short* K1T  = (unsigned short*)(ws + OFF_K1T);
  unsigned short* wbf  = (unsigned short*)(ws + OFF_WBF);
  float* diag = (float*)(ws + OFF_DIAG);
  float* ksum = (float*)(ws + OFF_KSUM);
  float* bnS  = (float*)(ws + OFF_BNS);
  float* bnQ  = (float*)(ws + OFF_BNQ);

  // K,V bf16 live in d_out until the final write (exactly 64MB)
  unsigned short* Kb = (unsigned short*)d_out;
  unsigned short* Vb = Kb + 16777216;

  hipMemsetAsync(ws + OFF_DIAG, 0, 16384 + 16384 + 2048 + 2048, stream);

  k_prep_w  <<<dim3(1024, 5),   256, 0, stream>>>(Wq, Wk, Wv, Wq1, Wk1, wbf);
  k_build_xs<<<dim3(64, 8, 8),  256, 0, stream>>>(x, pos, xsb);

  // 5 projection GEMMs
  gemm_bt<1><<<dim3(256, 4), 256, 0, stream>>>(xsb, wbf,            nullptr, Qb, bq,  512, nullptr, nullptr, nullptr);
  gemm_bt<1><<<dim3(256, 4), 256, 0, stream>>>(xsb, wbf + 262144,   nullptr, Kb, bk,  512, nullptr, nullptr, nullptr);
  gemm_bt<0><<<dim3(256, 4), 256, 0, stream>>>(xsb, wbf + 2*262144, nullptr, Vb, bv,  512, nullptr, nullptr, nullptr);
  gemm_bt<0><<<dim3(256, 4), 256, 0, stream>>>(xsb, wbf + 3*262144, nullptr, Q1, bq1, 512, nullptr, nullptr, nullptr);
  gemm_bt<0><<<dim3(256, 4), 256, 0, stream>>>(xsb, wbf + 4*262144, nullptr, K1, bk1, 512, nullptr, nullptr, nullptr);

  k_reduce_kv<<<dim3(8, 8, 8), 256, 0, stream>>>(Kb, Vb, diag, ksum);

  k_transpose_bf<<<dim3(64, 8, 8), 256, 0, stream>>>(Q1, Q1T, 4096, 512);
  k_transpose_bf<<<dim3(64, 8, 8), 256, 0, stream>>>(K1, K1T, 4096, 512);

  k_z_r0<<<dim3(8192), 256, 0, stream>>>(Qb, ksum, diag, r0);

  // mid logits: S[b][i][j] = sum_l Q1[l,i] K1[l,j]  (A=Q1T, Bt=K1T, K=4096)
  gemm_bt<2><<<dim3(4, 4, 8), 256, 0, stream>>>(Q1T, K1T, Sf, nullptr, nullptr, 4096, nullptr, nullptr, nullptr);

  k_softmax<<<dim3(4096), 64, 0, stream>>>(Sf, midb);
  k_transpose_bf<<<dim3(8, 8, 8), 256, 0, stream>>>(midb, midT, 512, 512);

  // result GEMM + residual + BN-stat epilogue (y in-place over xs_bf)
  gemm_bt<3><<<dim3(256, 4), 256, 0, stream>>>(r0, midT, nullptr, xsb, nullptr, 512, gam, bnS, bnQ);

  k_bn_finalize<<<dim3(64, 8, 8), 256, 0, stream>>>(xsb, bnS, bnQ, bnw, bnb, out);
}

// Round 2
// 297.535 us; speedup vs baseline: 1.3483x; 1.3483x over previous
//
#include <hip/hip_runtime.h>
#include <stdint.h>

typedef float f32x4 __attribute__((ext_vector_type(4)));
typedef short bf16x8 __attribute__((ext_vector_type(8)));
typedef short bf16x4 __attribute__((ext_vector_type(4)));

__device__ __forceinline__ float bf2f(unsigned short h){
  union { unsigned int u; float f; } v; v.u = ((unsigned int)h) << 16; return v.f;
}
__device__ __forceinline__ unsigned short f2bf(float f){
  union { float f; unsigned int u; } v; v.f = f;
  return (unsigned short)((v.u + 0x7fffu + ((v.u >> 16) & 1u)) >> 16);
}

typedef __attribute__((address_space(1))) const unsigned int ga_u32;
typedef __attribute__((address_space(3))) unsigned int ls_u32;
__device__ __forceinline__ void async_load16(const void* g, void* l){
  __builtin_amdgcn_global_load_lds((ga_u32*)g, (ls_u32*)l, 16, 0, 0);
}

// ---------------------------------------------------------------------------
// prep: fp32 weights -> bf16 (5 x 512x512), biases -> packed fp32 [5][512]
__global__ __launch_bounds__(256) void k_prep_w(
    const float* __restrict__ w0, const float* __restrict__ w1,
    const float* __restrict__ w2, const float* __restrict__ w3,
    const float* __restrict__ w4, unsigned short* __restrict__ out)
{
  int i = blockIdx.x * 256 + threadIdx.x;
  const float* w = (blockIdx.y == 0) ? w0 : (blockIdx.y == 1) ? w1 :
                   (blockIdx.y == 2) ? w2 : (blockIdx.y == 3) ? w3 : w4;
  out[(size_t)blockIdx.y * 262144 + i] = f2bf(w[i]);
}
__global__ __launch_bounds__(256) void k_prep_b(
    const float* __restrict__ b0, const float* __restrict__ b1,
    const float* __restrict__ b2, const float* __restrict__ b3,
    const float* __restrict__ b4, float* __restrict__ out)
{
  int i = blockIdx.x * 256 + threadIdx.x;   // 0..2559
  int s = i >> 9, r = i & 511;
  const float* b = (s == 0) ? b0 : (s == 1) ? b1 : (s == 2) ? b2 : (s == 3) ? b3 : b4;
  out[i] = b[r];
}

// ---------------------------------------------------------------------------
// build xs_bf[b][l][c] = bf16( x[b][c][l] + pos[l][c] )
__global__ __launch_bounds__(256) void k_build_xs(
    const float* __restrict__ x, const float* __restrict__ pos,
    unsigned short* __restrict__ xsb)
{
  __shared__ float tile[64][65];
  const int lt = blockIdx.x, ct = blockIdx.y, b = blockIdx.z;
  const int t = threadIdx.x;
  const int rr = t >> 3, c8 = (t & 7) * 8;
  #pragma unroll
  for (int pass = 0; pass < 2; pass++){
    int r = rr + pass * 32;
    const float* src = x + ((size_t)b * 512 + ct*64 + r) * 4096 + lt*64 + c8;
    f32x4 v0 = *(const f32x4*)src;
    f32x4 v1 = *(const f32x4*)(src + 4);
    #pragma unroll
    for (int s = 0; s < 4; s++){ tile[r][c8+s] = v0[s]; tile[r][c8+4+s] = v1[s]; }
  }
  __syncthreads();
  #pragma unroll
  for (int pass = 0; pass < 2; pass++){
    int ll = rr + pass * 32;
    int gl = lt*64 + ll;
    const float* pp = pos + (size_t)gl * 512 + ct*64 + c8;
    bf16x8 hv;
    #pragma unroll
    for (int s = 0; s < 8; s++)
      hv[s] = (short)f2bf(tile[c8+s][ll] + pp[s]);
    *(bf16x8*)(xsb + ((size_t)b * 4096 + gl) * 512 + ct*64 + c8) = hv;
  }
}

// ---------------------------------------------------------------------------
// generic bf16 transpose: in[z][R][C] -> out[z][C][R]   (used for mid only)
__global__ __launch_bounds__(256) void k_transpose_bf(
    const unsigned short* __restrict__ in, unsigned short* __restrict__ out,
    int R, int C)
{
  __shared__ float tile[64][65];
  const int rt = blockIdx.x, ct = blockIdx.y, z = blockIdx.z;
  const unsigned short* src = in  + (size_t)z * R * C;
  unsigned short*       dst = out + (size_t)z * R * C;
  const int t = threadIdx.x;
  const int rr = t >> 3, c8 = (t & 7) * 8;
  #pragma unroll
  for (int pass = 0; pass < 2; pass++){
    int r = rr + pass * 32;
    bf16x8 v = *(const bf16x8*)(src + (size_t)(rt*64 + r) * C + ct*64 + c8);
    #pragma unroll
    for (int s = 0; s < 8; s++) tile[r][c8+s] = bf2f((unsigned short)v[s]);
  }
  __syncthreads();
  #pragma unroll
  for (int pass = 0; pass < 2; pass++){
    int c = rr + pass * 32;
    bf16x8 hv;
    #pragma unroll
    for (int s = 0; s < 8; s++) hv[s] = (short)f2bf(tile[c8+s][c]);
    *(bf16x8*)(dst + (size_t)(ct*64 + c) * R + rt*64 + c8) = hv;
  }
}

// ---------------------------------------------------------------------------
// diagKV[b][c] = sum_l K*V ; Ksum[b][c] = sum_l K
__global__ __launch_bounds__(256) void k_reduce_kv(
    const unsigned short* __restrict__ Kb, const unsigned short* __restrict__ Vb,
    float* __restrict__ diag, float* __restrict__ ksum)
{
  const int c0 = blockIdx.x * 64, b = blockIdx.y, lz = blockIdx.z * 512;
  const int t = threadIdx.x;
  const int c = c0 + (t & 63), lo = t >> 6;
  float d = 0.f, s = 0.f;
  for (int l = lo; l < 512; l += 4){
    size_t idx = ((size_t)b * 4096 + lz + l) * 512 + c;
    float kk = bf2f(Kb[idx]);
    float vv = bf2f(Vb[idx]);
    d += kk * vv; s += kk;
  }
  __shared__ float sd[256], sk[256];
  sd[t] = d; sk[t] = s;
  __syncthreads();
  if (t < 64){
    d = sd[t] + sd[t+64] + sd[t+128] + sd[t+192];
    s = sk[t] + sk[t+64] + sk[t+128] + sk[t+192];
    atomicAdd(&diag[b*512 + c0 + t], d);
    atomicAdd(&ksum[b*512 + c0 + t], s);
  }
}

// ---------------------------------------------------------------------------
// per row: Z = 1/sum_c Q*(Ksum+eps); r0 = Q*diagKV*Z  (bf16 out)
__global__ __launch_bounds__(256) void k_z_r0(
    const unsigned short* __restrict__ Qb, const float* __restrict__ ksum,
    const float* __restrict__ diag, unsigned short* __restrict__ r0)
{
  const int row = blockIdx.x * 4 + (threadIdx.x >> 6);
  const int lane = threadIdx.x & 63;
  const int b = row >> 12;
  bf16x8 q = *(const bf16x8*)(Qb + (size_t)row * 512 + lane * 8);
  float qf[8];
  #pragma unroll
  for (int s = 0; s < 8; s++) qf[s] = bf2f((unsigned short)q[s]);
  f32x4 k0 = *(const f32x4*)(ksum + b*512 + lane*8);
  f32x4 k1 = *(const f32x4*)(ksum + b*512 + lane*8 + 4);
  f32x4 d0 = *(const f32x4*)(diag + b*512 + lane*8);
  f32x4 d1 = *(const f32x4*)(diag + b*512 + lane*8 + 4);
  float den = 0.f;
  #pragma unroll
  for (int s = 0; s < 4; s++) den += qf[s]   * (k0[s] + 1e-6f);
  #pragma unroll
  for (int s = 0; s < 4; s++) den += qf[4+s] * (k1[s] + 1e-6f);
  #pragma unroll
  for (int m = 1; m < 64; m <<= 1) den += __shfl_xor(den, m);
  float Z = 1.0f / den;
  bf16x8 hv;
  #pragma unroll
  for (int s = 0; s < 4; s++) hv[s]   = (short)f2bf(qf[s]   * d0[s] * Z);
  #pragma unroll
  for (int s = 0; s < 4; s++) hv[4+s] = (short)f2bf(qf[4+s] * d1[s] * Z);
  *(bf16x8*)(r0 + (size_t)row * 512 + lane * 8) = hv;
}

// ---------------------------------------------------------------------------
// row softmax: S[row][0..511] fp32 -> mid bf16
__global__ __launch_bounds__(64) void k_softmax(
    const float* __restrict__ S, unsigned short* __restrict__ mid)
{
  const size_t row = blockIdx.x;
  const int lane = threadIdx.x;
  const float* p = S + row * 512 + lane * 8;
  f32x4 v0 = *(const f32x4*)p, v1 = *(const f32x4*)(p + 4);
  float mx = v0[0];
  #pragma unroll
  for (int s = 1; s < 4; s++) mx = fmaxf(mx, v0[s]);
  #pragma unroll
  for (int s = 0; s < 4; s++) mx = fmaxf(mx, v1[s]);
  #pragma unroll
  for (int m = 1; m < 64; m <<= 1) mx = fmaxf(mx, __shfl_xor(mx, m));
  float e[8]; float sum = 0.f;
  #pragma unroll
  for (int s = 0; s < 4; s++){ e[s]   = __expf(v0[s] - mx); sum += e[s]; }
  #pragma unroll
  for (int s = 0; s < 4; s++){ e[4+s] = __expf(v1[s] - mx); sum += e[4+s]; }
  #pragma unroll
  for (int m = 1; m < 64; m <<= 1) sum += __shfl_xor(sum, m);
  float inv = 1.0f / sum;
  bf16x8 hv;
  #pragma unroll
  for (int s = 0; s < 8; s++) hv[s] = (short)f2bf(e[s] * inv);
  *(bf16x8*)(mid + row * 512 + lane * 8) = hv;
}

// ===========================================================================
// Shared GEMM machinery: 128x128 tile, BK=64, 4 waves, double-buffered LDS.
// LDS dest linear, global source XOR-pre-swizzled, reads XOR-swizzled.
// smem layout (ushort): A: [0,8192) buf0, [8192,16384) buf1
//                       B: [16384,24576) buf0, [24576,32768) buf1
// ===========================================================================
#define GEMM_PRE()                                                            \
  const int tid = threadIdx.x;                                                \
  const int lane = tid & 63;                                                  \
  const int wave = tid >> 6;                                                  \
  const int wm = wave >> 1, wn = wave & 1;                                    \
  size_t aoff[4], boff[4]; int ldsq[4];                                       \
  _Pragma("unroll")                                                           \
  for (int i = 0; i < 4; i++){                                                \
    int qq = i*4 + wave;                                                      \
    int ch = qq*64 + lane;                                                    \
    int m  = ch >> 3, p = ch & 7;                                             \
    int lc = p ^ (m & 7);                                                     \
    aoff[i] = (size_t)(m0 + m) * K + lc*8;                                    \
    boff[i] = (size_t)(n0 + m) * K + lc*8;                                    \
    ldsq[i] = qq * 1024;                                                      \
  }                                                                           \
  f32x4 acc[4][4];                                                            \
  const f32x4 vzero = {0.f,0.f,0.f,0.f};                                      \
  _Pragma("unroll")                                                           \
  for (int i = 0; i < 4; i++)                                                 \
    _Pragma("unroll")                                                         \
    for (int j = 0; j < 4; j++) acc[i][j] = vzero;                            \
  int arow[4], brow[4];                                                       \
  _Pragma("unroll")                                                           \
  for (int f = 0; f < 4; f++){                                                \
    arow[f] = (wm*64 + f*16 + (lane & 15)) * 64;                              \
    brow[f] = (wn*64 + f*16 + (lane & 15)) * 64;                              \
  }                                                                           \
  const int kg = lane >> 4;                                                   \
  const int l7 = lane & 7;

#define GEMM_STAGE(buf, kt)                                                   \
  _Pragma("unroll")                                                           \
  for (int i = 0; i < 4; i++){                                                \
    async_load16(Ae + aoff[i] + (kt)*64, (char*)&smem[(buf)*8192] + ldsq[i]); \
    async_load16(Be + boff[i] + (kt)*64, (char*)&smem[16384 + (buf)*8192] + ldsq[i]); \
  }

#define GEMM_COMPUTE(buf)                                                     \
  _Pragma("unroll")                                                           \
  for (int ks = 0; ks < 2; ks++){                                             \
    bf16x8 a[4], b[4];                                                        \
    const int pa = (ks*4 + kg) ^ l7;                                          \
    _Pragma("unroll")                                                         \
    for (int f = 0; f < 4; f++){                                              \
      a[f] = *(const bf16x8*)&smem[(buf)*8192 + arow[f] + pa*8];              \
      b[f] = *(const bf16x8*)&smem[16384 + (buf)*8192 + brow[f] + pa*8];      \
    }                                                                         \
    _Pragma("unroll")                                                         \
    for (int i = 0; i < 4; i++)                                               \
      _Pragma("unroll")                                                       \
      for (int j = 0; j < 4; j++)                                             \
        acc[i][j] = __builtin_amdgcn_mfma_f32_16x16x32_bf16(a[i], b[j], acc[i][j], 0, 0, 0); \
  }

#define GEMM_KLOOP(nkt)                                                       \
  GEMM_STAGE(0, 0);                                                           \
  __syncthreads();                                                            \
  int cur = 0;                                                                \
  for (int kt = 0; kt < (nkt); kt++){                                         \
    if (kt + 1 < (nkt)) { GEMM_STAGE(cur ^ 1, kt + 1); }                      \
    GEMM_COMPUTE(cur);                                                        \
    __syncthreads();                                                          \
    cur ^= 1;                                                                 \
  }

// ---------------------------------------------------------------------------
// fused 5-projection GEMM. A = xs [32768][512], Bt = wbf [5][512][512].
// grid = 5120 blocks, 1D, XCD-chunked.  nslot: 0-3 Q(relu), 4-7 K(relu),
// 8-11 V, 12-15 Q1 (transposed out), 16-19 K1 (transposed out).
__global__ __launch_bounds__(256) void gemm_proj(
    const unsigned short* __restrict__ A,
    const unsigned short* __restrict__ W,
    const float* __restrict__ bias5,
    unsigned short* __restrict__ Qb, unsigned short* __restrict__ Kb,
    unsigned short* __restrict__ Vb, unsigned short* __restrict__ Q1T,
    unsigned short* __restrict__ K1T)
{
  __shared__ unsigned short smem[32768];
  const int bid = blockIdx.x;
  const int wgid = (bid & 7) * 640 + (bid >> 3);   // 5120 % 8 == 0: bijective
  const int mtile = wgid / 20;
  const int nslot = wgid % 20;
  const int slot = nslot >> 2;
  const int ncol = nslot & 3;
  const int m0 = mtile * 128;
  const int n0 = ncol * 128;
  const int K = 512;
  const unsigned short* Ae = A;
  const unsigned short* Be = W + (size_t)slot * 262144;

  GEMM_PRE();
  GEMM_KLOOP(8);

  const int lr = lane >> 4;
  const int lc16 = lane & 15;

  if (slot < 3){
    unsigned short* o = (slot == 0) ? Qb : (slot == 1) ? Kb : Vb;
    const bool relu = (slot < 2);
    #pragma unroll
    for (int j = 0; j < 4; j++){
      int cl = n0 + wn*64 + j*16 + lc16;
      float bb = bias5[slot*512 + cl];
      #pragma unroll
      for (int i = 0; i < 4; i++){
        int r = m0 + wm*64 + i*16 + lr*4;
        #pragma unroll
        for (int q = 0; q < 4; q++){
          float v = acc[i][j][q] + bb;
          if (relu) v = v > 0.f ? v : 0.f;
          o[(size_t)(r + q) * 512 + cl] = f2bf(v);
        }
      }
    }
  } else {
    // transposed output: o[b][c][l], b = mtile>>5, l0 = (mtile&31)*128
    unsigned short* o = (slot == 3) ? Q1T : K1T;
    const int b = mtile >> 5;
    const int l0 = (mtile & 31) * 128;
    // write tile to LDS as [c_local 128][l_local 128], row stride 136 elems
    #pragma unroll
    for (int j = 0; j < 4; j++){
      int cl = wn*64 + j*16 + lc16;
      float bb = bias5[slot*512 + n0 + cl];
      #pragma unroll
      for (int i = 0; i < 4; i++){
        int ll = wm*64 + i*16 + lr*4;
        bf16x4 hv;
        #pragma unroll
        for (int q = 0; q < 4; q++) hv[q] = (short)f2bf(acc[i][j][q] + bb);
        *(bf16x4*)&smem[cl*136 + ll] = hv;
      }
    }
    __syncthreads();
    #pragma unroll
    for (int rep = 0; rep < 8; rep++){
      int c = rep*16 + (tid >> 4);
      int lch = tid & 15;
      bf16x8 v = *(const bf16x8*)&smem[c*136 + lch*8];
      *(bf16x8*)(o + ((size_t)b*512 + n0 + c)*4096 + l0 + lch*8) = v;
    }
  }
}

// ---------------------------------------------------------------------------
// gemm_core: EPI 2 = mid logits (fp32, per-batch); EPI 3 = result + BN stats
template<int EPI>
__global__ __launch_bounds__(256) void gemm_core(
    const unsigned short* __restrict__ A,
    const unsigned short* __restrict__ Bt,
    float* __restrict__ outf,
    unsigned short* __restrict__ outh,
    int K,
    const float* __restrict__ gamma_p,
    float* __restrict__ bnS,
    float* __restrict__ bnQ)
{
  __shared__ unsigned short smem[32768];
  const int bid = blockIdx.x;
  const int cpx = gridDim.x >> 3;
  const int wgid = (bid & 7) * cpx + (bid >> 3);
  int mtile, ntile, z = 0;
  if (EPI == 2){ z = wgid >> 4; mtile = (wgid >> 2) & 3; ntile = wgid & 3; }
  else         { mtile = wgid >> 2; ntile = wgid & 3; }
  const int m0 = mtile * 128, n0 = ntile * 128;
  const unsigned short* Ae = A;
  const unsigned short* Be = Bt;
  if (EPI == 2){ Ae += (size_t)z * 512 * (size_t)K; Be += (size_t)z * 512 * (size_t)K; }
  if (EPI == 3){ Be += (size_t)(mtile >> 5) * 262144; }

  GEMM_PRE();
  GEMM_KLOOP(K >> 6);

  const int lr = lane >> 4;
  const int lc16 = lane & 15;

  if constexpr (EPI == 2){
    #pragma unroll
    for (int j = 0; j < 4; j++){
      int cidx = n0 + wn*64 + j*16 + lc16;
      #pragma unroll
      for (int i = 0; i < 4; i++){
        int r = m0 + wm*64 + i*16 + lr*4;
        #pragma unroll
        for (int q = 0; q < 4; q++)
          outf[(size_t)z * 262144 + (size_t)(r + q) * 512 + cidx] = acc[i][j][q];
      }
    }
  } else {
    float g = gamma_p[0];
    float sc[4] = {0.f,0.f,0.f,0.f}, sq[4] = {0.f,0.f,0.f,0.f};
    #pragma unroll
    for (int j = 0; j < 4; j++){
      int cidx = n0 + wn*64 + j*16 + lc16;
      #pragma unroll
      for (int i = 0; i < 4; i++){
        int r = m0 + wm*64 + i*16 + lr*4;
        #pragma unroll
        for (int q = 0; q < 4; q++){
          size_t idx = (size_t)(r + q) * 512 + cidx;
          float y = bf2f(outh[idx]) + g * acc[i][j][q];
          outh[idx] = f2bf(y);
          sc[j] += y; sq[j] += y * y;
        }
      }
    }
    #pragma unroll
    for (int j = 0; j < 4; j++){
      #pragma unroll
      for (int m = 16; m < 64; m <<= 1){
        sc[j] += __shfl_xor(sc[j], m);
        sq[j] += __shfl_xor(sq[j], m);
      }
    }
    __syncthreads();
    float* sS = (float*)(void*)smem;         // 128 floats
    float* sQ = sS + 128;
    if (tid < 128){ sS[tid] = 0.f; sQ[tid] = 0.f; }
    __syncthreads();
    if (lr == 0){
      #pragma unroll
      for (int j = 0; j < 4; j++){
        atomicAdd(&sS[wn*64 + j*16 + lc16], sc[j]);
        atomicAdd(&sQ[wn*64 + j*16 + lc16], sq[j]);
      }
    }
    __syncthreads();
    if (tid < 128){
      atomicAdd(&bnS[n0 + tid], sS[tid]);
      atomicAdd(&bnQ[n0 + tid], sQ[tid]);
    }
  }
}

// ---------------------------------------------------------------------------
// finalize: y[b][l][c] bf16 -> out[b][c][l] fp32, BN affine + relu
__global__ __launch_bounds__(256) void k_bn_finalize(
    const unsigned short* __restrict__ y, const float* __restrict__ bnS,
    const float* __restrict__ bnQ, const float* __restrict__ bnw,
    const float* __restrict__ bnb, float* __restrict__ out)
{
  __shared__ float tile[64][65];
  __shared__ float scale_s[64], shift_s[64];
  const int lt = blockIdx.x, ct = blockIdx.y, b = blockIdx.z;
  const int t = threadIdx.x;
  if (t < 64){
    int c = ct*64 + t;
    float s = bnS[c], q = bnQ[c];
    float mean = s * (1.0f / 32768.0f);
    float var  = q * (1.0f / 32768.0f) - mean * mean;
    float inv  = rsqrtf(var + 1e-5f);
    float scv  = bnw[c] * inv;
    scale_s[t] = scv;
    shift_s[t] = bnb[c] - mean * scv;
  }
  const int rr = t >> 3, c8 = (t & 7) * 8;
  #pragma unroll
  for (int pass = 0; pass < 2; pass++){
    int l = rr + pass * 32;
    bf16x8 v = *(const bf16x8*)(y + ((size_t)b * 4096 + lt*64 + l) * 512 + ct*64 + c8);
    #pragma unroll
    for (int s = 0; s < 8; s++) tile[l][c8+s] = bf2f((unsigned short)v[s]);
  }
  __syncthreads();
  #pragma unroll
  for (int pass = 0; pass < 2; pass++){
    int c = rr + pass * 32;
    float scv = scale_s[c], sh = shift_s[c];
    f32x4 o0, o1;
    #pragma unroll
    for (int s = 0; s < 4; s++){
      float v = tile[c8+s][c] * scv + sh;     o0[s] = v > 0.f ? v : 0.f;
      float w = tile[c8+4+s][c] * scv + sh;   o1[s] = w > 0.f ? w : 0.f;
    }
    float* dp = out + ((size_t)b * 512 + ct*64 + c) * 4096 + lt*64 + c8;
    *(f32x4*)dp = o0;
    *(f32x4*)(dp + 4) = o1;
  }
}

// ---------------------------------------------------------------------------
extern "C" void kernel_launch(void* const* d_in, const int* in_sizes, int n_in,
                              void* d_out, int out_size, void* d_ws, size_t ws_size,
                              hipStream_t stream)
{
  const float* x    = (const float*)d_in[0];
  const float* pos  = (const float*)d_in[1];
  const float* Wq   = (const float*)d_in[2];
  const float* bq   = (const float*)d_in[3];
  const float* Wk   = (const float*)d_in[4];
  const float* bk   = (const float*)d_in[5];
  const float* Wv   = (const float*)d_in[6];
  const float* bv   = (const float*)d_in[7];
  const float* Wq1  = (const float*)d_in[8];
  const float* bq1  = (const float*)d_in[9];
  const float* Wk1  = (const float*)d_in[10];
  const float* bk1  = (const float*)d_in[11];
  const float* gam  = (const float*)d_in[12];
  const float* bnw  = (const float*)d_in[13];
  const float* bnb  = (const float*)d_in[14];
  float* out = (float*)d_out;
  char* ws = (char*)d_ws;

  const size_t MB = 1ull << 20;
  const size_t OFF_XSB  = 0;                  // 32MB xs_bf, later y in-place
  const size_t OFF_QB   = 32*MB;              // 32MB Q
  const size_t OFF_Q1T  = 64*MB;              // 32MB Q1^T [8][512][4096]
  const size_t OFF_K1T  = 96*MB;              // 32MB K1^T
  const size_t OFF_SF   = 128*MB;             // 8MB  S fp32 [8][512][512]
  const size_t OFF_MIDB = 136*MB;             // 4MB
  const size_t OFF_MIDT = 140*MB;             // 4MB
  const size_t OFF_R0   = 144*MB;             // 32MB
  const size_t OFF_WBF  = 176*MB;             // 2.5MB
  const size_t OFF_B5   = 179*MB;             // 10KB
  const size_t OFF_DIAG = 180*MB;
  const size_t OFF_KSUM = OFF_DIAG + 16384;
  const size_t OFF_BNS  = OFF_KSUM + 16384;
  const size_t OFF_BNQ  = OFF_BNS + 2048;
  const size_t WS_NEED  = OFF_BNQ + 2048;
  if (ws_size < WS_NEED) return;

  unsigned short* xsb  = (unsigned short*)(ws + OFF_XSB);
  unsigned short* Qb   = (unsigned short*)(ws + OFF_QB);
  unsigned short* Q1T  = (unsigned short*)(ws + OFF_Q1T);
  unsigned short* K1T  = (unsigned short*)(ws + OFF_K1T);
  float*          Sf   = (float*)(ws + OFF_SF);
  unsigned short* midb = (unsigned short*)(ws + OFF_MIDB);
  unsigned short* midT = (unsigned short*)(ws + OFF_MIDT);
  unsigned short* r0   = (unsigned short*)(ws + OFF_R0);
  unsigned short* wbf  = (unsigned short*)(ws + OFF_WBF);
  float* bias5 = (float*)(ws + OFF_B5);
  float* diag = (float*)(ws + OFF_DIAG);
  float* ksum = (float*)(ws + OFF_KSUM);
  float* bnS  = (float*)(ws + OFF_BNS);
  float* bnQ  = (float*)(ws + OFF_BNQ);

  unsigned short* Kb = (unsigned short*)d_out;        // K,V live in d_out
  unsigned short* Vb = Kb + 16777216;

  hipMemsetAsync(ws + OFF_DIAG, 0, 16384 + 16384 + 2048 + 2048, stream);

  k_prep_w  <<<dim3(1024, 5), 256, 0, stream>>>(Wq, Wk, Wv, Wq1, Wk1, wbf);
  k_prep_b  <<<dim3(10),      256, 0, stream>>>(bq, bk, bv, bq1, bk1, bias5);
  k_build_xs<<<dim3(64, 8, 8),256, 0, stream>>>(x, pos, xsb);

  // fused 5-projection GEMM (writes Q, K, V, Q1^T, K1^T)
  gemm_proj<<<dim3(5120), 256, 0, stream>>>(xsb, wbf, bias5, Qb, Kb, Vb, Q1T, K1T);

  k_reduce_kv<<<dim3(8, 8, 8), 256, 0, stream>>>(Kb, Vb, diag, ksum);
  k_z_r0<<<dim3(8192), 256, 0, stream>>>(Qb, ksum, diag, r0);

  // mid logits: S[b][i][j] = sum_l Q1[b,l,i] K1[b,l,j]  (A=Q1T, Bt=K1T, K=4096)
  gemm_core<2><<<dim3(128), 256, 0, stream>>>(Q1T, K1T, Sf, nullptr, 4096, nullptr, nullptr, nullptr);

  k_softmax<<<dim3(4096), 64, 0, stream>>>(Sf, midb);
  k_transpose_bf<<<dim3(8, 8, 8), 256, 0, stream>>>(midb, midT, 512, 512);

  // result GEMM + residual + BN-stat epilogue (y in-place over xs_bf)
  gemm_core<3><<<dim3(1024), 256, 0, stream>>>(r0, midT, nullptr, xsb, 512, gam, bnS, bnQ);

  k_bn_finalize<<<dim3(64, 8, 8), 256, 0, stream>>>(xsb, bnS, bnQ, bnw, bnb, out);
}